// Round 1
// baseline (822.388 us; speedup 1.0000x reference)
//
#include <hip/hip_runtime.h>

// Projection: out[b,f,e] = sum_d x[b, idx[f,d]] * W[f,d,e] + bias[f,e]
// B=524288, F=23, DMAX=4, E=10, TOTAL=65.  W is pre-masked (zeros past
// dims[f]) so the packed idx duplicates contribute nothing.
//
// Memory-bound: 136 MB read (x) + 482 MB write (out). W/b/idx = 4.6 KB,
// L1-resident. One thread per float2 of output -> coalesced dwordx2 stores.

#define PROJ_B     524288
#define PROJ_TOTAL 65
#define PROJ_F     23
#define PROJ_DMAX  4
#define PROJ_E     10
#define PROJ_COLS  (PROJ_F * PROJ_E)   // 230
#define PROJ_HALF  (PROJ_COLS / 2)     // 115 float2 per row

__global__ __launch_bounds__(256)
void Projection_5171140624940_kernel(const float* __restrict__ x,
                                     const float* __restrict__ W,
                                     const float* __restrict__ bias,
                                     const int*   __restrict__ idx,
                                     float*       __restrict__ out) {
    const int tid = blockIdx.x * blockDim.x + threadIdx.x;   // < B*115 < 2^31
    const int total = PROJ_B * PROJ_HALF;
    if (tid >= total) return;

    const int b  = tid / PROJ_HALF;               // row      (magic-mul)
    const int c2 = tid - b * PROJ_HALF;           // 0..114
    const int c  = c2 * 2;                        // even column 0..228
    const int f  = c / PROJ_E;                    // feature  (magic-mul)
    const int e  = c - f * PROJ_E;                // 0,2,4,6,8

    const float* __restrict__ xr = x + (long long)b * PROJ_TOTAL;

    // idx row: 16B aligned (f*4 ints), same for 5 consecutive lanes -> L1 broadcast
    const int4 id = *(const int4*)(idx + f * PROJ_DMAX);

    const float x0 = xr[id.x];
    const float x1 = xr[id.y];
    const float x2 = xr[id.z];
    const float x3 = xr[id.w];

    const float* __restrict__ Wf = W + f * (PROJ_DMAX * PROJ_E) + e;  // even offset
    const float2 w0 = *(const float2*)(Wf + 0 * PROJ_E);
    const float2 w1 = *(const float2*)(Wf + 1 * PROJ_E);
    const float2 w2 = *(const float2*)(Wf + 2 * PROJ_E);
    const float2 w3 = *(const float2*)(Wf + 3 * PROJ_E);

    float2 acc = *(const float2*)(bias + f * PROJ_E + e);             // even offset
    acc.x = fmaf(x0, w0.x, fmaf(x1, w1.x, fmaf(x2, w2.x, fmaf(x3, w3.x, acc.x))));
    acc.y = fmaf(x0, w0.y, fmaf(x1, w1.y, fmaf(x2, w2.y, fmaf(x3, w3.y, acc.y))));

    *(float2*)(out + (long long)b * PROJ_COLS + c) = acc;             // coalesced
}

extern "C" void kernel_launch(void* const* d_in, const int* in_sizes, int n_in,
                              void* d_out, int out_size, void* d_ws, size_t ws_size,
                              hipStream_t stream) {
    const float* x    = (const float*)d_in[0];   // (B, 65)
    const float* W    = (const float*)d_in[1];   // (23, 4, 10)
    const float* bias = (const float*)d_in[2];   // (23, 10)
    const int*   idx  = (const int*)d_in[3];     // (23, 4)
    float* out = (float*)d_out;                  // (B, 23, 10)

    const int total  = PROJ_B * PROJ_HALF;       // 60,293,120 threads
    const int block  = 256;
    const int grid   = (total + block - 1) / block;

    Projection_5171140624940_kernel<<<grid, block, 0, stream>>>(x, W, bias, idx, out);
}